// Round 1
// baseline (117.108 us; speedup 1.0000x reference)
//
#include <hip/hip_runtime.h>
#include <hip/hip_bf16.h>

// out[b][j] = sum_k x[b][k]*bmat[k][j]  (bf16 MFMA, HBM-bound on bmat)
//           + h[b][j]*a[j] + sum_r hq[b][r]*p[j][r]   (fused epilogue)
// hq = h @ q  (64x4) precomputed in d_ws.

#define HDIM 8192
#define BDIM 64
#define RDIM 4
#define BN 32
#define BK 128
#define KITERS (HDIM / BK)   // 64
#define LDK 136              // BK + 8 pad: col stride 272B -> 2-way bank alias (free)

typedef short short8 __attribute__((ext_vector_type(8)));
typedef float f32x4 __attribute__((ext_vector_type(4)));

__device__ __forceinline__ unsigned short f2bf(float f) {
  // round-to-nearest-even f32 -> bf16 (finite inputs)
  unsigned u = __float_as_uint(f);
  unsigned r = u + 0x7fffu + ((u >> 16) & 1u);
  return (unsigned short)(r >> 16);
}

// ---- prep: x (f32) -> xb (bf16 bits), row-major [64][8192] ----
__global__ void prep_x_kernel(const float* __restrict__ x,
                              unsigned short* __restrict__ xb) {
  size_t i = ((size_t)blockIdx.x * blockDim.x + threadIdx.x) * 8;
  f32x4 v0 = *(const f32x4*)(x + i);
  f32x4 v1 = *(const f32x4*)(x + i + 4);
  union { unsigned short u[8]; short8 s; } o;
#pragma unroll
  for (int e = 0; e < 4; ++e) { o.u[e] = f2bf(v0[e]); o.u[4 + e] = f2bf(v1[e]); }
  *(short8*)(xb + i) = o.s;
}

// ---- hq[b][r] = sum_k h[b][k] * q[k][r] ; one block per batch row ----
__global__ void hq_kernel(const float* __restrict__ h,
                          const float* __restrict__ q,
                          float* __restrict__ hq) {
  const int b = blockIdx.x, t = threadIdx.x;
  const float* hrow = h + (size_t)b * HDIM;
  f32x4 s = {0.f, 0.f, 0.f, 0.f};
  for (int k = t; k < HDIM; k += 256) {
    float hv = hrow[k];
    f32x4 qv = *(const f32x4*)(q + (size_t)k * RDIM);
    s += hv * qv;
  }
  __shared__ f32x4 red[256];
  red[t] = s;
  __syncthreads();
  for (int off = 128; off > 0; off >>= 1) {
    if (t < off) red[t] += red[t + off];
    __syncthreads();
  }
  if (t == 0) *(f32x4*)(hq + (size_t)b * RDIM) = red[0];
}

// ---- main: C(64x8192) = Xbf16 @ Bbf16 + epilogue, grid = 256 blocks ----
__global__ __launch_bounds__(512)
void dplr_main(const float* __restrict__ bmat,
               const unsigned short* __restrict__ xb,
               const float* __restrict__ h,
               const float* __restrict__ adiag,
               const float* __restrict__ pvec,
               const float* __restrict__ hq,
               float* __restrict__ out) {
  __shared__ __align__(16) unsigned short ldsb[2][BN][LDK];  // [buf][col j][k], bf16 bits

  const int t    = threadIdx.x;
  const int lane = t & 63;
  const int w    = t >> 6;        // 8 waves
  const int mt   = w & 3;         // M tile 0..3 (rows 16*mt..)
  const int nt   = w >> 2;        // N tile 0..1 (cols 16*nt..)
  const int j0   = blockIdx.x * BN;
  const int col  = lane & 15;
  const int kgrp = lane >> 4;     // 0..3
  const int arow = 16 * mt + col;

  // staging map: thread t loads float4s; 8 threads cover one 128B row of 32 cols
  const int skl = t >> 3;         // k_local 0..63
  const int sj  = (t & 7) * 4;    // col base 0,4,..,28
  const float* bbase = bmat + (size_t)j0 + sj;

  f32x4 acc = {0.f, 0.f, 0.f, 0.f};
  f32x4 r0, r1;

  auto issue = [&](int ki) {
    const float* p = bbase + (size_t)(ki * BK + skl) * HDIM;
    r0 = *(const f32x4*)p;
    r1 = *(const f32x4*)(p + (size_t)64 * HDIM);
  };
  auto stage = [&](int buf) {
#pragma unroll
    for (int jj = 0; jj < 4; ++jj) ldsb[buf][sj + jj][skl]      = f2bf(r0[jj]);
#pragma unroll
    for (int jj = 0; jj < 4; ++jj) ldsb[buf][sj + jj][64 + skl] = f2bf(r1[jj]);
  };

  issue(0);
  stage(0);
  __syncthreads();

  const unsigned short* xrow = xb + (size_t)arow * HDIM;
  const unsigned short* bcol = &ldsb[0][nt * 16 + col][0];
  const size_t bufstride = (size_t)BN * LDK;  // shorts per buffer

  for (int ki = 0; ki < KITERS; ++ki) {
    const int cur = ki & 1;
    if (ki + 1 < KITERS) issue(ki + 1);   // next tile's 16KB in flight during MFMA
#pragma unroll
    for (int s = 0; s < 4; ++s) {         // 4 x K=32 steps
      const int kk = s * 32 + kgrp * 8;
      short8 af = *(const short8*)(xrow + (size_t)ki * BK + kk);
      short8 bf = *(const short8*)(bcol + (size_t)cur * bufstride + kk);
      acc = __builtin_amdgcn_mfma_f32_16x16x32_bf16(af, bf, acc, 0, 0, 0);
    }
    if (ki + 1 < KITERS) stage(cur ^ 1);
    __syncthreads();
  }

  // epilogue: + h*a + hq @ p^T ; C layout: col = lane&15, row = (lane>>4)*4 + r
  const int j = j0 + nt * 16 + col;
  const float av = adiag[j];
  const f32x4 pv = *(const f32x4*)(pvec + (size_t)j * RDIM);
  const int rbase = 16 * mt + kgrp * 4;
#pragma unroll
  for (int r = 0; r < 4; ++r) {
    const int row = rbase + r;
    const float hv = h[(size_t)row * HDIM + j];
    const f32x4 hqv = *(const f32x4*)(hq + (size_t)row * RDIM);
    out[(size_t)row * HDIM + j] =
        acc[r] + hv * av + hqv[0] * pv[0] + hqv[1] * pv[1] + hqv[2] * pv[2] + hqv[3] * pv[3];
  }
}

extern "C" void kernel_launch(void* const* d_in, const int* in_sizes, int n_in,
                              void* d_out, int out_size, void* d_ws, size_t ws_size,
                              hipStream_t stream) {
  const float* h     = (const float*)d_in[0];
  const float* x     = (const float*)d_in[1];
  const float* adiag = (const float*)d_in[2];
  const float* pvec  = (const float*)d_in[3];
  const float* qvec  = (const float*)d_in[4];
  const float* bmat  = (const float*)d_in[5];
  float* out = (float*)d_out;

  unsigned short* xb = (unsigned short*)d_ws;                       // 64*8192*2 = 1 MiB
  float* hqbuf = (float*)((char*)d_ws + (size_t)BDIM * HDIM * 2);   // 64*4*4 = 1 KiB

  prep_x_kernel<<<(BDIM * HDIM / 8) / 256, 256, 0, stream>>>(x, xb);
  hq_kernel<<<BDIM, 256, 0, stream>>>(h, qvec, hqbuf);
  dplr_main<<<HDIM / BN, 512, 0, stream>>>(bmat, xb, h, adiag, pvec, hqbuf, out);
}

// Round 2
// 113.803 us; speedup vs baseline: 1.0290x; 1.0290x over previous
//
#include <hip/hip_runtime.h>
#include <hip/hip_bf16.h>

// out[b][j] = sum_k x[b][k]*bmat[k][j]  (bf16 MFMA, HBM-bound on bmat f32 stream)
//           + h[b][j]*a[j] + sum_r hq[b][r]*p[j][r]   (fused epilogue)
// hq = h @ q  (64x4) precomputed in d_ws.

#define HDIM 8192
#define BDIM 64
#define RDIM 4
#define BN 32
#define BK 256
#define KITERS (HDIM / BK)   // 32

typedef short short8 __attribute__((ext_vector_type(8)));
typedef float f32x4 __attribute__((ext_vector_type(4)));
typedef unsigned int uint2v __attribute__((ext_vector_type(2)));

__device__ __forceinline__ unsigned f2bf(float f) {
  // round-to-nearest-even f32 -> bf16 (finite inputs); low 16 bits valid
  unsigned u = __float_as_uint(f);
  unsigned r = u + 0x7fffu + ((u >> 16) & 1u);
  return r >> 16;
}

// LDS layout: per column (0..31) 256 shorts; 16B granules XOR/add-swizzled so
// ds_read_b128 (16 cols x 4 kgrps) and ds_write_b64 (8 j-lanes x k-quads) are
// both bank-uniform. phys granule = (g&~7) | ((g + (col>>2) + 2*(col&3)) & 7).
__device__ __forceinline__ int swz(int colIdx, int kk) {
  int g = kk >> 3;
  int f = (colIdx >> 2) + 2 * (colIdx & 3);
  int pg = (g & ~7) | ((g + f) & 7);
  return colIdx * BK + (pg << 3) + (kk & 7);
}

// ---- prep: x (f32) -> xb (bf16 bits), row-major [64][8192] ----
__global__ void prep_x_kernel(const float* __restrict__ x,
                              unsigned short* __restrict__ xb) {
  size_t i = ((size_t)blockIdx.x * blockDim.x + threadIdx.x) * 8;
  f32x4 v0 = *(const f32x4*)(x + i);
  f32x4 v1 = *(const f32x4*)(x + i + 4);
  union { unsigned short u[8]; short8 s; } o;
#pragma unroll
  for (int e = 0; e < 4; ++e) {
    o.u[e] = (unsigned short)f2bf(v0[e]);
    o.u[4 + e] = (unsigned short)f2bf(v1[e]);
  }
  *(short8*)(xb + i) = o.s;
}

// ---- hq[b][r] = sum_k h[b][k] * q[k][r] ; one block per batch row ----
__global__ void hq_kernel(const float* __restrict__ h,
                          const float* __restrict__ q,
                          float* __restrict__ hq) {
  const int b = blockIdx.x, t = threadIdx.x;
  const float* hrow = h + (size_t)b * HDIM;
  f32x4 s = {0.f, 0.f, 0.f, 0.f};
  for (int k = t; k < HDIM; k += 256) {
    float hv = hrow[k];
    f32x4 qv = *(const f32x4*)(q + (size_t)k * RDIM);
    s += hv * qv;
  }
  __shared__ f32x4 red[256];
  red[t] = s;
  __syncthreads();
  for (int off = 128; off > 0; off >>= 1) {
    if (t < off) red[t] += red[t + off];
    __syncthreads();
  }
  if (t == 0) *(f32x4*)(hq + (size_t)b * RDIM) = red[0];
}

// ---- main: C(64x8192) = Xbf16 @ Bbf16 + epilogue, grid = 256 blocks ----
__global__ __launch_bounds__(512)
void dplr_main(const float* __restrict__ bmat,
               const unsigned short* __restrict__ xb,
               const float* __restrict__ h,
               const float* __restrict__ adiag,
               const float* __restrict__ pvec,
               const float* __restrict__ hq,
               float* __restrict__ out) {
  __shared__ __align__(16) unsigned short ldsb[2 * BN * BK];  // 32 KiB

  const int t    = threadIdx.x;
  const int lane = t & 63;
  const int w    = t >> 6;        // 8 waves
  const int mt   = w & 3;         // M tile 0..3 (rows 16*mt..)
  const int nt   = w >> 2;        // N tile 0..1 (cols 16*nt..)
  const int j0   = blockIdx.x * BN;
  const int col  = lane & 15;
  const int kgrp = lane >> 4;     // 0..3

  // staging map: thread t covers 4 cols (sj..sj+3) x 4 k-adjacent rows (kb..kb+3)
  const int sj = (t & 7) * 4;
  const int kb = (t >> 3) * 4;    // 0..252
  const float* bbase = bmat + (size_t)j0 + sj;

  f32x4 acc = {0.f, 0.f, 0.f, 0.f};
  f32x4 A0, A1, A2, A3, B0, B1, B2, B3;   // 2-tile-deep register prefetch

  auto issue = [&](int ki, f32x4& p0, f32x4& p1, f32x4& p2, f32x4& p3) {
    const float* p = bbase + (size_t)(ki * BK + kb) * HDIM;
    p0 = *(const f32x4*)p;
    p1 = *(const f32x4*)(p + HDIM);
    p2 = *(const f32x4*)(p + 2 * HDIM);
    p3 = *(const f32x4*)(p + 3 * HDIM);
  };
  auto stage = [&](int buf, const f32x4& p0, const f32x4& p1,
                   const f32x4& p2, const f32x4& p3) {
    unsigned short* b = ldsb + buf * (BN * BK);
#pragma unroll
    for (int jj = 0; jj < 4; ++jj) {
      uint2v v;
      v.x = f2bf(p0[jj]) | (f2bf(p1[jj]) << 16);
      v.y = f2bf(p2[jj]) | (f2bf(p3[jj]) << 16);
      *(uint2v*)&b[swz(sj + jj, kb)] = v;   // 8B store, 8B-aligned
    }
  };

  const unsigned short* xrow = xb + (size_t)(16 * mt + col) * HDIM;
  const int rcol = nt * 16 + col;

  auto mfma_tile = [&](int ki, int buf) {
    const unsigned short* b = ldsb + buf * (BN * BK);
#pragma unroll
    for (int s = 0; s < 8; ++s) {
      const int kk = s * 32 + kgrp * 8;
      short8 af = *(const short8*)(xrow + (size_t)ki * BK + kk);
      short8 bf = *(const short8*)&b[swz(rcol, kk)];
      acc = __builtin_amdgcn_mfma_f32_16x16x32_bf16(af, bf, acc, 0, 0, 0);
    }
  };

  issue(0, A0, A1, A2, A3);
  issue(1, B0, B1, B2, B3);
  stage(0, A0, A1, A2, A3);
  __syncthreads();

  for (int ki = 0; ki < KITERS; ki += 2) {
    if (ki + 2 < KITERS) issue(ki + 2, A0, A1, A2, A3);
    mfma_tile(ki, ki & 1);
    stage((ki + 1) & 1, B0, B1, B2, B3);
    __syncthreads();
    if (ki + 3 < KITERS) issue(ki + 3, B0, B1, B2, B3);
    mfma_tile(ki + 1, (ki + 1) & 1);
    if (ki + 2 < KITERS) stage((ki + 2) & 1, A0, A1, A2, A3);
    __syncthreads();
  }

  // epilogue: + h*a + hq @ p^T ; C layout: col = lane&15, row = (lane>>4)*4 + r
  const int j = j0 + nt * 16 + col;
  const float av = adiag[j];
  const f32x4 pv = *(const f32x4*)(pvec + (size_t)j * RDIM);
  const int rbase = 16 * mt + kgrp * 4;
#pragma unroll
  for (int r = 0; r < 4; ++r) {
    const int row = rbase + r;
    const float hv = h[(size_t)row * HDIM + j];
    const f32x4 hqv = *(const f32x4*)(hq + (size_t)row * RDIM);
    out[(size_t)row * HDIM + j] =
        acc[r] + hv * av + hqv[0] * pv[0] + hqv[1] * pv[1] + hqv[2] * pv[2] + hqv[3] * pv[3];
  }
}

extern "C" void kernel_launch(void* const* d_in, const int* in_sizes, int n_in,
                              void* d_out, int out_size, void* d_ws, size_t ws_size,
                              hipStream_t stream) {
  const float* h     = (const float*)d_in[0];
  const float* x     = (const float*)d_in[1];
  const float* adiag = (const float*)d_in[2];
  const float* pvec  = (const float*)d_in[3];
  const float* qvec  = (const float*)d_in[4];
  const float* bmat  = (const float*)d_in[5];
  float* out = (float*)d_out;

  unsigned short* xb = (unsigned short*)d_ws;                       // 64*8192*2 = 1 MiB
  float* hqbuf = (float*)((char*)d_ws + (size_t)BDIM * HDIM * 2);   // 64*4*4 = 1 KiB

  prep_x_kernel<<<(BDIM * HDIM / 8) / 256, 256, 0, stream>>>(x, xb);
  hq_kernel<<<BDIM, 256, 0, stream>>>(h, qvec, hqbuf);
  dplr_main<<<HDIM / BN, 512, 0, stream>>>(bmat, xb, h, adiag, pvec, hqbuf, out);
}

// Round 4
// 104.730 us; speedup vs baseline: 1.1182x; 1.0866x over previous
//
#include <hip/hip_runtime.h>
#include <hip/hip_bf16.h>

// out = x @ bmat + h*a + (h@q) @ p^T, M=64 N=8192 K=8192, bmat f32 streamed once.
// Split-K GEMM: 16 col-groups (BN=512) x 16 k-slabs (KSLAB=512) = 256 blocks.
// Each block reads bmat in 2KB-contiguous row segments (DRAM-row friendly).
// Partials f32 -> d_ws; combine kernel reduces 16 slices + fused epilogue.

#define HDIM 8192
#define BDIM 64
#define RDIM 4
#define BN 512
#define KSPLIT 16
#define KSLAB 512           // HDIM / KSPLIT
#define BK 32
#define NITER (KSLAB / BK)  // 16

typedef short short8 __attribute__((ext_vector_type(8)));
typedef float f32x4 __attribute__((ext_vector_type(4)));
typedef unsigned int uint2v __attribute__((ext_vector_type(2)));

__device__ __forceinline__ unsigned f2bf(float f) {
  // round-to-nearest-even f32 -> bf16 (finite inputs); low 16 bits valid
  unsigned u = __float_as_uint(f);
  unsigned r = u + 0x7fffu + ((u >> 16) & 1u);
  return r >> 16;
}

// ---- prep: x (f32) -> xb (bf16 bits), row-major [64][8192] ----
__global__ void prep_x_kernel(const float* __restrict__ x,
                              unsigned short* __restrict__ xb) {
  size_t i = ((size_t)blockIdx.x * blockDim.x + threadIdx.x) * 8;
  f32x4 v0 = *(const f32x4*)(x + i);
  f32x4 v1 = *(const f32x4*)(x + i + 4);
  union { unsigned short u[8]; short8 s; } o;
#pragma unroll
  for (int e = 0; e < 4; ++e) {
    o.u[e] = (unsigned short)f2bf(v0[e]);
    o.u[4 + e] = (unsigned short)f2bf(v1[e]);
  }
  *(short8*)(xb + i) = o.s;
}

// ---- hq[b][r] = sum_k h[b][k] * q[k][r] ; one block per batch row ----
__global__ void hq_kernel(const float* __restrict__ h,
                          const float* __restrict__ q,
                          float* __restrict__ hq) {
  const int b = blockIdx.x, t = threadIdx.x;
  const float* hrow = h + (size_t)b * HDIM;
  f32x4 s = {0.f, 0.f, 0.f, 0.f};
  for (int k = t; k < HDIM; k += 256) {
    float hv = hrow[k];
    f32x4 qv = *(const f32x4*)(q + (size_t)k * RDIM);
    s += hv * qv;
  }
  __shared__ f32x4 red[256];
  red[t] = s;
  __syncthreads();
  for (int off = 128; off > 0; off >>= 1) {
    if (t < off) red[t] += red[t + off];
    __syncthreads();
  }
  if (t == 0) *(f32x4*)(hq + (size_t)b * RDIM) = red[0];
}

// ---- main: partial C for one (jg, ks): 64 x 512 over K=512 ----
// LDS per col: 32 shorts = 4 granules of 16B; phys granule = g ^ f(col),
// f(col) = ((col>>1) ^ (col>>3)) & 3. Verified bank-uniform for both
// ds_write_b64 staging (4-k packs) and ds_read_b128 B-fragments.
__global__ __launch_bounds__(512)
void dplr_main(const float* __restrict__ bmat,
               const unsigned short* __restrict__ xb,
               float* __restrict__ part) {
  __shared__ __align__(16) unsigned short ldsb[2][BN * BK];  // 2 x 32 KiB

  const int t    = threadIdx.x;
  const int lane = t & 63;
  const int w    = t >> 6;        // 8 waves: 4 M-tiles x 2 N-halves
  const int mt   = w & 3;
  const int nt   = w >> 2;
  const int c    = lane & 15;
  const int kgrp = lane >> 4;     // 0..3

  const int jg = blockIdx.x & 15;
  const int ks = blockIdx.x >> 4;
  const int j0 = jg * BN;
  const int k0 = ks * KSLAB;

  // staging map: thread covers 4 k-rows (quad kq) x 8 cols (group cg)
  const int kq = t & 7;           // row-quad 0..7 (rows 4kq..4kq+3 of BK)
  const int cg = t >> 3;          // 0..63, cols cg*8..cg*8+7
  const float* bbase = bmat + (size_t)(k0 + kq * 4) * HDIM + j0 + cg * 8;

  f32x4 L[8];                     // 4 rows x 32B
  auto issue = [&](int ki) {
    const float* p = bbase + (size_t)ki * BK * HDIM;
#pragma unroll
    for (int rr = 0; rr < 4; ++rr) {
      L[rr * 2]     = *(const f32x4*)(p + (size_t)rr * HDIM);
      L[rr * 2 + 1] = *(const f32x4*)(p + (size_t)rr * HDIM + 4);
    }
  };
  auto stage = [&](int buf) {
    unsigned short* b = ldsb[buf];
#pragma unroll
    for (int jj = 0; jj < 8; ++jj) {
      const int col = cg * 8 + jj;
      const int f   = ((col >> 1) ^ (col >> 3)) & 3;
      const int gp  = ((kq >> 1) ^ f) & 3;
      uint2v v;
      v.x = f2bf(L[(jj >> 2)][jj & 3])     | (f2bf(L[2 + (jj >> 2)][jj & 3]) << 16);
      v.y = f2bf(L[4 + (jj >> 2)][jj & 3]) | (f2bf(L[6 + (jj >> 2)][jj & 3]) << 16);
      *(uint2v*)&b[col * 32 + gp * 8 + (kq & 1) * 4] = v;
    }
  };

  const unsigned short* xrow = xb + (size_t)(16 * mt + c) * HDIM + k0;

  f32x4 acc[16];
#pragma unroll
  for (int n = 0; n < 16; ++n) acc[n] = (f32x4){0.f, 0.f, 0.f, 0.f};

  issue(0);
  stage(0);
  __syncthreads();

  for (int ki = 0; ki < NITER; ++ki) {
    if (ki + 1 < NITER) issue(ki + 1);   // 64KB/block in flight during MFMA
    const unsigned short* b = ldsb[ki & 1];
    short8 af = *(const short8*)(xrow + ki * BK + kgrp * 8);
#pragma unroll
    for (int n = 0; n < 16; ++n) {
      const int col = nt * 256 + n * 16 + c;
      const int f   = ((col >> 1) ^ (col >> 3)) & 3;
      const int gp  = (kgrp ^ f) & 3;
      short8 bf = *(const short8*)&b[col * 32 + gp * 8];
      acc[n] = __builtin_amdgcn_mfma_f32_16x16x32_bf16(af, bf, acc[n], 0, 0, 0);
    }
    if (ki + 1 < NITER) stage((ki + 1) & 1);
    __syncthreads();
  }

  // write partial tile [64][512] contiguous per block
  float* pb = part + (size_t)(ks * 16 + jg) * BDIM * BN;
#pragma unroll
  for (int n = 0; n < 16; ++n) {
    const int col = nt * 256 + n * 16 + c;
#pragma unroll
    for (int r = 0; r < 4; ++r) {
      const int row = mt * 16 + kgrp * 4 + r;
      pb[(size_t)row * BN + col] = acc[n][r];
    }
  }
}

// ---- combine: out = sum_ks part + h*a + hq @ p^T ----
__global__ __launch_bounds__(256)
void combine_kernel(const float* __restrict__ part,
                    const float* __restrict__ h,
                    const float* __restrict__ adiag,
                    const float* __restrict__ pvec,
                    const float* __restrict__ hq,
                    float* __restrict__ out) {
  const int tid  = blockIdx.x * 256 + threadIdx.x;
  const int base = tid * 8;            // flat into [64][8192]
  const int row  = base >> 13;
  const int j    = base & 8191;
  const int jg   = j >> 9;
  const int jc   = j & 511;

  f32x4 s0 = {0.f, 0.f, 0.f, 0.f}, s1 = {0.f, 0.f, 0.f, 0.f};
  const float* pp = part + (size_t)jg * BDIM * BN + (size_t)row * BN + jc;
#pragma unroll
  for (int ks = 0; ks < KSPLIT; ++ks) {
    const float* q = pp + (size_t)ks * 16 * BDIM * BN;
    s0 += *(const f32x4*)q;
    s1 += *(const f32x4*)(q + 4);
  }
  const f32x4 hv0 = *(const f32x4*)(h + (size_t)row * HDIM + j);
  const f32x4 hv1 = *(const f32x4*)(h + (size_t)row * HDIM + j + 4);
  const f32x4 a0  = *(const f32x4*)(adiag + j);
  const f32x4 a1  = *(const f32x4*)(adiag + j + 4);
  const f32x4 hqv = *(const f32x4*)(hq + (size_t)row * RDIM);

  float res[8];
#pragma unroll
  for (int e = 0; e < 4; ++e) {
    const f32x4 pv = *(const f32x4*)(pvec + (size_t)(j + e) * RDIM);
    res[e] = s0[e] + hv0[e] * a0[e] +
             hqv[0] * pv[0] + hqv[1] * pv[1] + hqv[2] * pv[2] + hqv[3] * pv[3];
  }
#pragma unroll
  for (int e = 0; e < 4; ++e) {
    const f32x4 pv = *(const f32x4*)(pvec + (size_t)(j + 4 + e) * RDIM);
    res[4 + e] = s1[e] + hv1[e] * a1[e] +
                 hqv[0] * pv[0] + hqv[1] * pv[1] + hqv[2] * pv[2] + hqv[3] * pv[3];
  }
  f32x4 o0 = {res[0], res[1], res[2], res[3]};
  f32x4 o1 = {res[4], res[5], res[6], res[7]};
  *(f32x4*)(out + (size_t)row * HDIM + j) = o0;
  *(f32x4*)(out + (size_t)row * HDIM + j + 4) = o1;
}

extern "C" void kernel_launch(void* const* d_in, const int* in_sizes, int n_in,
                              void* d_out, int out_size, void* d_ws, size_t ws_size,
                              hipStream_t stream) {
  const float* h     = (const float*)d_in[0];
  const float* x     = (const float*)d_in[1];
  const float* adiag = (const float*)d_in[2];
  const float* pvec  = (const float*)d_in[3];
  const float* qvec  = (const float*)d_in[4];
  const float* bmat  = (const float*)d_in[5];
  float* out = (float*)d_out;

  unsigned short* xb = (unsigned short*)d_ws;                        // 1 MiB
  float* hqbuf = (float*)((char*)d_ws + ((size_t)1 << 20));          // 1 KiB
  float* part  = (float*)((char*)d_ws + ((size_t)2 << 20));          // 32 MiB

  prep_x_kernel<<<(BDIM * HDIM / 8) / 256, 256, 0, stream>>>(x, xb);
  hq_kernel<<<BDIM, 256, 0, stream>>>(h, qvec, hqbuf);
  dplr_main<<<KSPLIT * 16, 512, 0, stream>>>(bmat, xb, part);
  combine_kernel<<<(BDIM * HDIM / 8) / 256, 256, 0, stream>>>(part, h, adiag, pvec, hqbuf, out);
}

// Round 5
// 83.512 us; speedup vs baseline: 1.4023x; 1.2541x over previous
//
#include <hip/hip_runtime.h>
#include <hip/hip_bf16.h>

// out = x @ bmat + h*a + (h@q) @ p^T ; M=64, N=K=8192, bmat f32 streamed once.
// Barrier-free streaming GEMM: x-slab staged in LDS once per block; bmat goes
// global->register directly as MFMA B-fragments (no LDS, no barriers, no
// vmcnt(0) drains in the main loop). 512 blocks x 512 thr = 16 waves/CU all
// independently streaming => continuous HBM request flow (m13-copy regime).
// Partials [ks][64][8192] f32 -> combine kernel (+ fused DPLR epilogue).

#define HDIM 8192
#define BDIM 64
#define RDIM 4
#define KSPLIT 16
#define KSLAB 512            // HDIM / KSPLIT
#define JGRP 256             // cols per block (8 waves x 32)
#define NKSTEP (KSLAB / 32)  // 16

typedef short short8 __attribute__((ext_vector_type(8)));
typedef float f32x4 __attribute__((ext_vector_type(4)));

__device__ __forceinline__ unsigned f2bf(float f) {
  // round-to-nearest-even f32 -> bf16 (finite inputs); low 16 bits valid
  unsigned u = __float_as_uint(f);
  unsigned r = u + 0x7fffu + ((u >> 16) & 1u);
  return r >> 16;
}

// ---- prep: x (f32) -> xb (bf16 bits), row-major [64][8192] ----
__global__ void prep_x_kernel(const float* __restrict__ x,
                              unsigned short* __restrict__ xb) {
  size_t i = ((size_t)blockIdx.x * blockDim.x + threadIdx.x) * 8;
  f32x4 v0 = *(const f32x4*)(x + i);
  f32x4 v1 = *(const f32x4*)(x + i + 4);
  union { unsigned short u[8]; short8 s; } o;
#pragma unroll
  for (int e = 0; e < 4; ++e) {
    o.u[e] = (unsigned short)f2bf(v0[e]);
    o.u[4 + e] = (unsigned short)f2bf(v1[e]);
  }
  *(short8*)(xb + i) = o.s;
}

// ---- hq[b][r] = sum_k h[b][k] * q[k][r] ; one block per batch row ----
__global__ void hq_kernel(const float* __restrict__ h,
                          const float* __restrict__ q,
                          float* __restrict__ hq) {
  const int b = blockIdx.x, t = threadIdx.x;
  const float* hrow = h + (size_t)b * HDIM;
  f32x4 s = {0.f, 0.f, 0.f, 0.f};
  for (int k = t; k < HDIM; k += 256) {
    float hv = hrow[k];
    f32x4 qv = *(const f32x4*)(q + (size_t)k * RDIM);
    s += hv * qv;
  }
  __shared__ f32x4 red[256];
  red[t] = s;
  __syncthreads();
  for (int off = 128; off > 0; off >>= 1) {
    if (t < off) red[t] += red[t + off];
    __syncthreads();
  }
  if (t == 0) *(f32x4*)(hq + (size_t)b * RDIM) = red[0];
}

// ---- main: partial C for one (jg, ks): 64 x 256 over K=512 ----
// x-LDS: 64 rows x 512 k bf16, 16B granules; phys granule g' = g ^ (row&7).
// Verified bank-balanced (8 lanes/quad = LDS floor) for stage-write b128 and
// per-mt fragment ds_read_b128.
__global__ __launch_bounds__(512, 4)
void dplr_main(const float* __restrict__ bmat,
               const unsigned short* __restrict__ xb,
               float* __restrict__ part) {
  __shared__ __align__(16) unsigned short xs[BDIM * KSLAB];  // 64 KiB

  const int t    = threadIdx.x;
  const int lane = t & 63;
  const int w    = t >> 6;        // 8 waves, wave w owns cols j0..j0+31
  const int c    = lane & 15;
  const int kgrp = lane >> 4;     // 0..3

  const int jg = blockIdx.x & 31;
  const int ks = blockIdx.x >> 5;
  const int k0 = ks * KSLAB;

  // ---- stage x slab once (rows 0..63, k in [k0, k0+512)) ----
  {
    const int row = t >> 3;
    const int kq0 = (t & 7) * 8;         // granule base within row (64 granules/row)
    const unsigned short* src = xb + (size_t)row * HDIM + k0 + kq0 * 8;
#pragma unroll
    for (int i = 0; i < 8; ++i) {
      const int g  = row * (KSLAB / 8) + kq0 + i;
      const int gs = g ^ (row & 7);
      *(short8*)&xs[gs * 8] = *(const short8*)(src + i * 8);
    }
  }
  __syncthreads();   // the only barrier in this kernel

  const int j0 = jg * JGRP + w * 32;
  const float* b0 = bmat + (size_t)(k0 + kgrp * 8) * HDIM + j0 + c;

  f32x4 acc[4][2];
#pragma unroll
  for (int mt = 0; mt < 4; ++mt)
#pragma unroll
    for (int ct = 0; ct < 2; ++ct) acc[mt][ct] = (f32x4){0.f, 0.f, 0.f, 0.f};

  for (int ki = 0; ki < NKSTEP; ++ki) {
    // B fragments: 8 k-rows x 2 col-tiles, direct global loads (f32)
    float f0[8], f1[8];
#pragma unroll
    for (int i = 0; i < 8; ++i) {
      const float* p = b0 + (size_t)(ki * 32 + i) * HDIM;
      f0[i] = p[0];
      f1[i] = p[16];
    }
    union { unsigned short u[8]; short8 s; } bf0, bf1;
#pragma unroll
    for (int i = 0; i < 8; ++i) {
      bf0.u[i] = (unsigned short)f2bf(f0[i]);
      bf1.u[i] = (unsigned short)f2bf(f1[i]);
    }
#pragma unroll
    for (int mt = 0; mt < 4; ++mt) {
      const int row = mt * 16 + c;
      const int g   = row * (KSLAB / 8) + ki * 4 + kgrp;
      const int gs  = g ^ (row & 7);
      short8 af = *(const short8*)&xs[gs * 8];
      acc[mt][0] = __builtin_amdgcn_mfma_f32_16x16x32_bf16(af, bf0.s, acc[mt][0], 0, 0, 0);
      acc[mt][1] = __builtin_amdgcn_mfma_f32_16x16x32_bf16(af, bf1.s, acc[mt][1], 0, 0, 0);
    }
  }

  // partial write: part[ks][row][j], rows 64, full-width 8192 layout
  float* pb = part + (size_t)ks * BDIM * HDIM;
#pragma unroll
  for (int mt = 0; mt < 4; ++mt)
#pragma unroll
    for (int ct = 0; ct < 2; ++ct)
#pragma unroll
      for (int r = 0; r < 4; ++r) {
        const int row = mt * 16 + kgrp * 4 + r;
        const int col = j0 + ct * 16 + c;
        pb[(size_t)row * HDIM + col] = acc[mt][ct][r];
      }
}

// ---- combine: out = sum_ks part + h*a + hq @ p^T ----
__global__ __launch_bounds__(256)
void combine_kernel(const float* __restrict__ part,
                    const float* __restrict__ h,
                    const float* __restrict__ adiag,
                    const float* __restrict__ pvec,
                    const float* __restrict__ hq,
                    float* __restrict__ out) {
  const int tid  = blockIdx.x * 256 + threadIdx.x;
  const int base = tid * 8;            // flat into [64][8192]
  const int row  = base >> 13;
  const int j    = base & 8191;

  f32x4 s0 = {0.f, 0.f, 0.f, 0.f}, s1 = {0.f, 0.f, 0.f, 0.f};
  const float* pp = part + (size_t)row * HDIM + j;
#pragma unroll
  for (int ks = 0; ks < KSPLIT; ++ks) {
    const float* q = pp + (size_t)ks * BDIM * HDIM;
    s0 += *(const f32x4*)q;
    s1 += *(const f32x4*)(q + 4);
  }
  const f32x4 hv0 = *(const f32x4*)(h + (size_t)row * HDIM + j);
  const f32x4 hv1 = *(const f32x4*)(h + (size_t)row * HDIM + j + 4);
  const f32x4 a0  = *(const f32x4*)(adiag + j);
  const f32x4 a1  = *(const f32x4*)(adiag + j + 4);
  const f32x4 hqv = *(const f32x4*)(hq + (size_t)row * RDIM);

  float res[8];
#pragma unroll
  for (int e = 0; e < 4; ++e) {
    const f32x4 pv = *(const f32x4*)(pvec + (size_t)(j + e) * RDIM);
    res[e] = s0[e] + hv0[e] * a0[e] +
             hqv[0] * pv[0] + hqv[1] * pv[1] + hqv[2] * pv[2] + hqv[3] * pv[3];
  }
#pragma unroll
  for (int e = 0; e < 4; ++e) {
    const f32x4 pv = *(const f32x4*)(pvec + (size_t)(j + 4 + e) * RDIM);
    res[4 + e] = s1[e] + hv1[e] * a1[e] +
                 hqv[0] * pv[0] + hqv[1] * pv[1] + hqv[2] * pv[2] + hqv[3] * pv[3];
  }
  f32x4 o0 = {res[0], res[1], res[2], res[3]};
  f32x4 o1 = {res[4], res[5], res[6], res[7]};
  *(f32x4*)(out + (size_t)row * HDIM + j) = o0;
  *(f32x4*)(out + (size_t)row * HDIM + j + 4) = o1;
}

extern "C" void kernel_launch(void* const* d_in, const int* in_sizes, int n_in,
                              void* d_out, int out_size, void* d_ws, size_t ws_size,
                              hipStream_t stream) {
  const float* h     = (const float*)d_in[0];
  const float* x     = (const float*)d_in[1];
  const float* adiag = (const float*)d_in[2];
  const float* pvec  = (const float*)d_in[3];
  const float* qvec  = (const float*)d_in[4];
  const float* bmat  = (const float*)d_in[5];
  float* out = (float*)d_out;

  unsigned short* xb = (unsigned short*)d_ws;                        // 1 MiB
  float* hqbuf = (float*)((char*)d_ws + ((size_t)1 << 20));          // 1 KiB
  float* part  = (float*)((char*)d_ws + ((size_t)2 << 20));          // 32 MiB

  prep_x_kernel<<<(BDIM * HDIM / 8) / 256, 256, 0, stream>>>(x, xb);
  hq_kernel<<<BDIM, 256, 0, stream>>>(h, qvec, hqbuf);
  dplr_main<<<KSPLIT * 32, 512, 0, stream>>>(bmat, xb, part);
  combine_kernel<<<(BDIM * HDIM / 8) / 256, 256, 0, stream>>>(part, h, adiag, pvec, hqbuf, out);
}

// Round 6
// 77.798 us; speedup vs baseline: 1.5053x; 1.0734x over previous
//
#include <hip/hip_runtime.h>
#include <hip/hip_bf16.h>

// out = x @ bmat + h*a + (h@q) @ p^T ; M=64, N=K=8192, bmat f32 streamed once.
// Barrier-free streaming GEMM + depth-2 register pipeline on the bmat loads.
// x-slab staged in LDS once per block; bmat goes global->register directly as
// MFMA B-fragments. No barriers / vmcnt(0) drains in the main loop; loads for
// tile k+1 are in flight while tile k is converted+MFMA'd.
// Partials bf16 [ks][64][8192] -> combine kernel (+ fused DPLR epilogue).

#define HDIM 8192
#define BDIM 64
#define RDIM 4
#define KSPLIT 16
#define KSLAB 512            // HDIM / KSPLIT
#define JGRP 256             // cols per block (8 waves x 32)
#define NKSTEP (KSLAB / 32)  // 16

typedef short short8 __attribute__((ext_vector_type(8)));
typedef float f32x4 __attribute__((ext_vector_type(4)));

__device__ __forceinline__ unsigned f2bf(float f) {
  // round-to-nearest-even f32 -> bf16 (finite inputs); low 16 bits valid
  unsigned u = __float_as_uint(f);
  unsigned r = u + 0x7fffu + ((u >> 16) & 1u);
  return r >> 16;
}

__device__ __forceinline__ float bf2f(unsigned short u) {
  return __uint_as_float(((unsigned)u) << 16);
}

// ---- prep: x (f32) -> xb (bf16 bits), row-major [64][8192] ----
__global__ void prep_x_kernel(const float* __restrict__ x,
                              unsigned short* __restrict__ xb) {
  size_t i = ((size_t)blockIdx.x * blockDim.x + threadIdx.x) * 8;
  f32x4 v0 = *(const f32x4*)(x + i);
  f32x4 v1 = *(const f32x4*)(x + i + 4);
  union { unsigned short u[8]; short8 s; } o;
#pragma unroll
  for (int e = 0; e < 4; ++e) {
    o.u[e] = (unsigned short)f2bf(v0[e]);
    o.u[4 + e] = (unsigned short)f2bf(v1[e]);
  }
  *(short8*)(xb + i) = o.s;
}

// ---- hq[b][r] = sum_k h[b][k] * q[k][r] ; one block per batch row ----
__global__ void hq_kernel(const float* __restrict__ h,
                          const float* __restrict__ q,
                          float* __restrict__ hq) {
  const int b = blockIdx.x, t = threadIdx.x;
  const float* hrow = h + (size_t)b * HDIM;
  f32x4 s = {0.f, 0.f, 0.f, 0.f};
  for (int k = t; k < HDIM; k += 256) {
    float hv = hrow[k];
    f32x4 qv = *(const f32x4*)(q + (size_t)k * RDIM);
    s += hv * qv;
  }
  __shared__ f32x4 red[256];
  red[t] = s;
  __syncthreads();
  for (int off = 128; off > 0; off >>= 1) {
    if (t < off) red[t] += red[t + off];
    __syncthreads();
  }
  if (t == 0) *(f32x4*)(hq + (size_t)b * RDIM) = red[0];
}

// ---- main: partial C for one (jg, ks): 64 x 256 over K=512 ----
// x-LDS: 64 rows x 512 k bf16, 16B granules; phys granule g' = g ^ (row&7).
__global__ __launch_bounds__(512, 4)
void dplr_main(const float* __restrict__ bmat,
               const unsigned short* __restrict__ xb,
               unsigned short* __restrict__ part) {
  __shared__ __align__(16) unsigned short xs[BDIM * KSLAB];  // 64 KiB

  const int t    = threadIdx.x;
  const int lane = t & 63;
  const int w    = t >> 6;        // 8 waves, wave w owns cols j0..j0+31
  const int c    = lane & 15;
  const int kgrp = lane >> 4;     // 0..3

  const int jg = blockIdx.x & 31;
  const int ks = blockIdx.x >> 5;
  const int k0 = ks * KSLAB;

  // ---- stage x slab once (rows 0..63, k in [k0, k0+512)) ----
  {
    const int row = t >> 3;
    const int kq0 = (t & 7) * 8;         // granule base within row (64 granules/row)
    const unsigned short* src = xb + (size_t)row * HDIM + k0 + kq0 * 8;
#pragma unroll
    for (int i = 0; i < 8; ++i) {
      const int g  = row * (KSLAB / 8) + kq0 + i;
      const int gs = g ^ (row & 7);
      *(short8*)&xs[gs * 8] = *(const short8*)(src + i * 8);
    }
  }
  __syncthreads();   // the only barrier in this kernel

  const int j0 = jg * JGRP + w * 32;
  const float* b0 = bmat + (size_t)(k0 + kgrp * 8) * HDIM + j0 + c;

  f32x4 acc[4][2];
#pragma unroll
  for (int mt = 0; mt < 4; ++mt)
#pragma unroll
    for (int ct = 0; ct < 2; ++ct) acc[mt][ct] = (f32x4){0.f, 0.f, 0.f, 0.f};

  float fA0[8], fA1[8], fB0[8], fB1[8];

  auto issue = [&](int ki, float* g0, float* g1) {
#pragma unroll
    for (int i = 0; i < 8; ++i) {
      const float* p = b0 + (size_t)(ki * 32 + i) * HDIM;
      g0[i] = p[0];
      g1[i] = p[16];
    }
  };
  auto conv_mfma = [&](int ki, const float* g0, const float* g1) {
    union { unsigned short u[8]; short8 s; } bf0, bf1;
#pragma unroll
    for (int i = 0; i < 8; ++i) {
      bf0.u[i] = (unsigned short)f2bf(g0[i]);
      bf1.u[i] = (unsigned short)f2bf(g1[i]);
    }
#pragma unroll
    for (int mt = 0; mt < 4; ++mt) {
      const int row = mt * 16 + c;
      const int g   = row * (KSLAB / 8) + ki * 4 + kgrp;
      const int gs  = g ^ (row & 7);
      short8 af = *(const short8*)&xs[gs * 8];
      acc[mt][0] = __builtin_amdgcn_mfma_f32_16x16x32_bf16(af, bf0.s, acc[mt][0], 0, 0, 0);
      acc[mt][1] = __builtin_amdgcn_mfma_f32_16x16x32_bf16(af, bf1.s, acc[mt][1], 0, 0, 0);
    }
  };

  issue(0, fA0, fA1);
  for (int ki = 0; ki < NKSTEP; ki += 2) {
    issue(ki + 1, fB0, fB1);                       // tile ki+1 in flight
    conv_mfma(ki, fA0, fA1);                       // consume tile ki (vmcnt(16))
    if (ki + 2 < NKSTEP) issue(ki + 2, fA0, fA1);  // tile ki+2 in flight
    conv_mfma(ki + 1, fB0, fB1);                   // consume tile ki+1
  }

  // partial write (bf16): part[ks][row][j], rows 64, full-width 8192 layout
  unsigned short* pb = part + (size_t)ks * BDIM * HDIM;
#pragma unroll
  for (int mt = 0; mt < 4; ++mt)
#pragma unroll
    for (int ct = 0; ct < 2; ++ct)
#pragma unroll
      for (int r = 0; r < 4; ++r) {
        const int row = mt * 16 + kgrp * 4 + r;
        const int col = j0 + ct * 16 + c;
        pb[(size_t)row * HDIM + col] = (unsigned short)f2bf(acc[mt][ct][r]);
      }
}

// ---- combine: out = sum_ks part + h*a + hq @ p^T ----
__global__ __launch_bounds__(256)
void combine_kernel(const unsigned short* __restrict__ part,
                    const float* __restrict__ h,
                    const float* __restrict__ adiag,
                    const float* __restrict__ pvec,
                    const float* __restrict__ hq,
                    float* __restrict__ out) {
  const int tid  = blockIdx.x * 256 + threadIdx.x;
  const int base = tid * 8;            // flat into [64][8192]
  const int row  = base >> 13;
  const int j    = base & 8191;

  float s[8];
#pragma unroll
  for (int e = 0; e < 8; ++e) s[e] = 0.f;
  const unsigned short* pp = part + (size_t)row * HDIM + j;
#pragma unroll
  for (int ks = 0; ks < KSPLIT; ++ks) {
    union { unsigned short u[8]; short8 v; } pv;
    pv.v = *(const short8*)(pp + (size_t)ks * BDIM * HDIM);
#pragma unroll
    for (int e = 0; e < 8; ++e) s[e] += bf2f(pv.u[e]);
  }
  const f32x4 hv0 = *(const f32x4*)(h + (size_t)row * HDIM + j);
  const f32x4 hv1 = *(const f32x4*)(h + (size_t)row * HDIM + j + 4);
  const f32x4 a0  = *(const f32x4*)(adiag + j);
  const f32x4 a1  = *(const f32x4*)(adiag + j + 4);
  const f32x4 hqv = *(const f32x4*)(hq + (size_t)row * RDIM);

  float res[8];
#pragma unroll
  for (int e = 0; e < 4; ++e) {
    const f32x4 pv = *(const f32x4*)(pvec + (size_t)(j + e) * RDIM);
    res[e] = s[e] + hv0[e] * a0[e] +
             hqv[0] * pv[0] + hqv[1] * pv[1] + hqv[2] * pv[2] + hqv[3] * pv[3];
  }
#pragma unroll
  for (int e = 0; e < 4; ++e) {
    const f32x4 pv = *(const f32x4*)(pvec + (size_t)(j + 4 + e) * RDIM);
    res[4 + e] = s[4 + e] + hv1[e] * a1[e] +
                 hqv[0] * pv[0] + hqv[1] * pv[1] + hqv[2] * pv[2] + hqv[3] * pv[3];
  }
  f32x4 o0 = {res[0], res[1], res[2], res[3]};
  f32x4 o1 = {res[4], res[5], res[6], res[7]};
  *(f32x4*)(out + (size_t)row * HDIM + j) = o0;
  *(f32x4*)(out + (size_t)row * HDIM + j + 4) = o1;
}

extern "C" void kernel_launch(void* const* d_in, const int* in_sizes, int n_in,
                              void* d_out, int out_size, void* d_ws, size_t ws_size,
                              hipStream_t stream) {
  const float* h     = (const float*)d_in[0];
  const float* x     = (const float*)d_in[1];
  const float* adiag = (const float*)d_in[2];
  const float* pvec  = (const float*)d_in[3];
  const float* qvec  = (const float*)d_in[4];
  const float* bmat  = (const float*)d_in[5];
  float* out = (float*)d_out;

  unsigned short* xb = (unsigned short*)d_ws;                           // 1 MiB
  float* hqbuf = (float*)((char*)d_ws + ((size_t)1 << 20));             // 1 KiB
  unsigned short* part = (unsigned short*)((char*)d_ws + ((size_t)2 << 20));  // 16 MiB

  prep_x_kernel<<<(BDIM * HDIM / 8) / 256, 256, 0, stream>>>(x, xb);
  hq_kernel<<<BDIM, 256, 0, stream>>>(h, qvec, hqbuf);
  dplr_main<<<KSPLIT * 32, 512, 0, stream>>>(bmat, xb, part);
  combine_kernel<<<(BDIM * HDIM / 8) / 256, 256, 0, stream>>>(part, h, adiag, pvec, hqbuf, out);
}

// Round 7
// 76.293 us; speedup vs baseline: 1.5350x; 1.0197x over previous
//
#include <hip/hip_runtime.h>
#include <hip/hip_bf16.h>

// out = x @ bmat + h*a + (h@q) @ p^T ; M=64, N=K=8192, bmat f32 streamed once.
// Barrier-free streaming GEMM, 32x32x16 MFMA fragments so each direct
// global_load_dword covers 2 full aligned 128B lines (cols = lane&31).
// Depth-2 register pipeline on bmat loads; x-slab in LDS (XOR-swizzled).
// Partials bf16 [ks][64][8192] -> combine kernel (+ fused DPLR epilogue).

#define HDIM 8192
#define BDIM 64
#define RDIM 4
#define KSPLIT 16
#define KSLAB 512            // HDIM / KSPLIT
#define JGRP 256             // cols per block (8 waves x 32)
#define NKSTEP (KSLAB / 32)  // 16 tiles of 32 k

typedef short short8 __attribute__((ext_vector_type(8)));
typedef float f32x4 __attribute__((ext_vector_type(4)));
typedef float f32x16 __attribute__((ext_vector_type(16)));

__device__ __forceinline__ unsigned f2bf(float f) {
  // round-to-nearest-even f32 -> bf16 (finite inputs); low 16 bits valid
  unsigned u = __float_as_uint(f);
  unsigned r = u + 0x7fffu + ((u >> 16) & 1u);
  return r >> 16;
}

__device__ __forceinline__ float bf2f(unsigned short u) {
  return __uint_as_float(((unsigned)u) << 16);
}

// ---- prep: x row b -> bf16, and hq[b] = h[b] @ q ; one block per row ----
__global__ __launch_bounds__(256)
void prep_hq_kernel(const float* __restrict__ x,
                    const float* __restrict__ h,
                    const float* __restrict__ q,
                    unsigned short* __restrict__ xb,
                    float* __restrict__ hq) {
  const int b = blockIdx.x, t = threadIdx.x;
  // x convert: 8192 f32 -> 1024 short8 chunks, 4 per thread
  {
    const float* xrow = x + (size_t)b * HDIM;
    unsigned short* xo = xb + (size_t)b * HDIM;
#pragma unroll
    for (int i = 0; i < 4; ++i) {
      const int base = (t * 4 + i) * 8;
      f32x4 v0 = *(const f32x4*)(xrow + base);
      f32x4 v1 = *(const f32x4*)(xrow + base + 4);
      union { unsigned short u[8]; short8 s; } o;
#pragma unroll
      for (int e = 0; e < 4; ++e) {
        o.u[e] = (unsigned short)f2bf(v0[e]);
        o.u[4 + e] = (unsigned short)f2bf(v1[e]);
      }
      *(short8*)(xo + base) = o.s;
    }
  }
  // hq reduction
  const float* hrow = h + (size_t)b * HDIM;
  f32x4 s = {0.f, 0.f, 0.f, 0.f};
  for (int k = t; k < HDIM; k += 256) {
    float hv = hrow[k];
    f32x4 qv = *(const f32x4*)(q + (size_t)k * RDIM);
    s += hv * qv;
  }
  __shared__ f32x4 red[256];
  red[t] = s;
  __syncthreads();
  for (int off = 128; off > 0; off >>= 1) {
    if (t < off) red[t] += red[t + off];
    __syncthreads();
  }
  if (t == 0) *(f32x4*)(hq + (size_t)b * RDIM) = red[0];
}

// ---- main: partial C for one (jg, ks): 64 x 256 over K=512 ----
// x-LDS: 64 rows x 512 k bf16, 16B granules; phys granule g' = g ^ (row&7).
__global__ __launch_bounds__(512, 4)
void dplr_main(const float* __restrict__ bmat,
               const unsigned short* __restrict__ xb,
               unsigned short* __restrict__ part) {
  __shared__ __align__(16) unsigned short xs[BDIM * KSLAB];  // 64 KiB

  const int t    = threadIdx.x;
  const int lane = t & 63;
  const int w    = t >> 6;        // 8 waves, wave w owns cols j0..j0+31
  const int c32  = lane & 31;
  const int kh   = lane >> 5;     // 0..1 (k-half of the 32x32x16 fragment)

  const int jg = blockIdx.x & 31;
  const int ks = blockIdx.x >> 5;
  const int k0 = ks * KSLAB;

  // ---- stage x slab once (rows 0..63, k in [k0, k0+512)) ----
  {
    const int row = t >> 3;
    const int kq0 = (t & 7) * 8;         // granule base within row (64/row)
    const unsigned short* src = xb + (size_t)row * HDIM + k0 + kq0 * 8;
#pragma unroll
    for (int i = 0; i < 8; ++i) {
      const int g  = row * (KSLAB / 8) + kq0 + i;
      const int gs = g ^ (row & 7);
      *(short8*)&xs[gs * 8] = *(const short8*)(src + i * 8);
    }
  }
  __syncthreads();   // the only barrier in this kernel

  const int j0 = jg * JGRP + w * 32;
  // lane's load column: j0 + c32 ; lane's k offset: kh*8
  const float* b0 = bmat + (size_t)(k0 + kh * 8) * HDIM + j0 + c32;

  f32x16 acc[2];
#pragma unroll
  for (int mt = 0; mt < 2; ++mt)
#pragma unroll
    for (int r = 0; r < 16; ++r) acc[mt][r] = 0.f;

  float fA[16], fB[16];

  // one 32-k tile = 2 MFMA k-steps of 16; per step 8 dword loads.
  // each load instr: 64 lanes = 2 rows x 32 cols x 4B = 2 full 128B lines.
  auto issue = [&](int ki, float* g) {
#pragma unroll
    for (int s = 0; s < 2; ++s)
#pragma unroll
      for (int i = 0; i < 8; ++i)
        g[s * 8 + i] = b0[(size_t)(ki * 32 + s * 16 + i) * HDIM];
  };
  auto conv_mfma = [&](int ki, const float* g) {
#pragma unroll
    for (int s = 0; s < 2; ++s) {
      union { unsigned short u[8]; short8 v; } bf;
#pragma unroll
      for (int i = 0; i < 8; ++i) bf.u[i] = (unsigned short)f2bf(g[s * 8 + i]);
#pragma unroll
      for (int mt = 0; mt < 2; ++mt) {
        const int row = mt * 32 + c32;                    // A row (batch)
        const int gg  = row * (KSLAB / 8) + ki * 4 + s * 2 + kh;
        const int gs  = gg ^ (row & 7);
        short8 af = *(const short8*)&xs[gs * 8];
        acc[mt] = __builtin_amdgcn_mfma_f32_32x32x16_bf16(af, bf.v, acc[mt], 0, 0, 0);
      }
    }
  };

  issue(0, fA);
  for (int ki = 0; ki < NKSTEP; ki += 2) {
    issue(ki + 1, fB);                       // tile ki+1 in flight
    conv_mfma(ki, fA);                       // consume tile ki (vmcnt(16))
    if (ki + 2 < NKSTEP) issue(ki + 2, fA);  // tile ki+2 in flight
    conv_mfma(ki + 1, fB);                   // consume tile ki+1
  }

  // partial write (bf16): part[ks][row][j]
  // C/D layout (32x32): col = lane&31, row = (reg&3) + 8*(reg>>2) + 4*kh
  unsigned short* pb = part + (size_t)ks * BDIM * HDIM;
#pragma unroll
  for (int mt = 0; mt < 2; ++mt)
#pragma unroll
    for (int reg = 0; reg < 16; ++reg) {
      const int row = mt * 32 + (reg & 3) + 8 * (reg >> 2) + 4 * kh;
      const int col = j0 + c32;
      pb[(size_t)row * HDIM + col] = (unsigned short)f2bf(acc[mt][reg]);
    }
}

// ---- combine: out = sum_ks part + h*a + hq @ p^T ----
__global__ __launch_bounds__(256)
void combine_kernel(const unsigned short* __restrict__ part,
                    const float* __restrict__ h,
                    const float* __restrict__ adiag,
                    const float* __restrict__ pvec,
                    const float* __restrict__ hq,
                    float* __restrict__ out) {
  const int tid  = blockIdx.x * 256 + threadIdx.x;
  const int base = tid * 8;            // flat into [64][8192]
  const int row  = base >> 13;
  const int j    = base & 8191;

  float s[8];
#pragma unroll
  for (int e = 0; e < 8; ++e) s[e] = 0.f;
  const unsigned short* pp = part + (size_t)row * HDIM + j;
#pragma unroll
  for (int ks = 0; ks < KSPLIT; ++ks) {
    union { unsigned short u[8]; short8 v; } pv;
    pv.v = *(const short8*)(pp + (size_t)ks * BDIM * HDIM);
#pragma unroll
    for (int e = 0; e < 8; ++e) s[e] += bf2f(pv.u[e]);
  }
  const f32x4 hv0 = *(const f32x4*)(h + (size_t)row * HDIM + j);
  const f32x4 hv1 = *(const f32x4*)(h + (size_t)row * HDIM + j + 4);
  const f32x4 a0  = *(const f32x4*)(adiag + j);
  const f32x4 a1  = *(const f32x4*)(adiag + j + 4);
  const f32x4 hqv = *(const f32x4*)(hq + (size_t)row * RDIM);

  float res[8];
#pragma unroll
  for (int e = 0; e < 4; ++e) {
    const f32x4 pv = *(const f32x4*)(pvec + (size_t)(j + e) * RDIM);
    res[e] = s[e] + hv0[e] * a0[e] +
             hqv[0] * pv[0] + hqv[1] * pv[1] + hqv[2] * pv[2] + hqv[3] * pv[3];
  }
#pragma unroll
  for (int e = 0; e < 4; ++e) {
    const f32x4 pv = *(const f32x4*)(pvec + (size_t)(j + 4 + e) * RDIM);
    res[4 + e] = s[4 + e] + hv1[e] * a1[e] +
                 hqv[0] * pv[0] + hqv[1] * pv[1] + hqv[2] * pv[2] + hqv[3] * pv[3];
  }
  f32x4 o0 = {res[0], res[1], res[2], res[3]};
  f32x4 o1 = {res[4], res[5], res[6], res[7]};
  *(f32x4*)(out + (size_t)row * HDIM + j) = o0;
  *(f32x4*)(out + (size_t)row * HDIM + j + 4) = o1;
}

extern "C" void kernel_launch(void* const* d_in, const int* in_sizes, int n_in,
                              void* d_out, int out_size, void* d_ws, size_t ws_size,
                              hipStream_t stream) {
  const float* h     = (const float*)d_in[0];
  const float* x     = (const float*)d_in[1];
  const float* adiag = (const float*)d_in[2];
  const float* pvec  = (const float*)d_in[3];
  const float* qvec  = (const float*)d_in[4];
  const float* bmat  = (const float*)d_in[5];
  float* out = (float*)d_out;

  unsigned short* xb = (unsigned short*)d_ws;                           // 1 MiB
  float* hqbuf = (float*)((char*)d_ws + ((size_t)1 << 20));             // 1 KiB
  unsigned short* part = (unsigned short*)((char*)d_ws + ((size_t)2 << 20));  // 16 MiB

  prep_hq_kernel<<<BDIM, 256, 0, stream>>>(x, h, qvec, xb, hqbuf);
  dplr_main<<<KSPLIT * 32, 512, 0, stream>>>(bmat, xb, part);
  combine_kernel<<<(BDIM * HDIM / 8) / 256, 256, 0, stream>>>(part, h, adiag, pvec, hqbuf, out);
}

// Round 8
// 73.214 us; speedup vs baseline: 1.5995x; 1.0421x over previous
//
#include <hip/hip_runtime.h>
#include <hip/hip_bf16.h>

// out = x @ bmat + h*a + (h@q) @ p^T ; M=64, N=K=8192, bmat f32 streamed once.
// Barrier-free streaming GEMM. Wave tile = 64 rows x 64 cols: each
// global_load_dword reads ONE fully-contiguous 256B segment of a bmat row
// (col = j0 + lane). v_permlane32_swap_b32 redistributes the 64-col data into
// two 32x32x16 B-fragments in-register (no LDS, no shuffle tables).
// Depth-2 register pipeline; x-slab in LDS (XOR-swizzled). Partials bf16
// [ks][64][8192] -> combine kernel (+ fused DPLR epilogue).

#define HDIM 8192
#define BDIM 64
#define RDIM 4
#define KSPLIT 16
#define KSLAB 512            // HDIM / KSPLIT
#define NKTILE (KSLAB / 32)  // 16 tiles of 32 k

typedef short short8 __attribute__((ext_vector_type(8)));
typedef float f32x4 __attribute__((ext_vector_type(4)));
typedef float f32x16 __attribute__((ext_vector_type(16)));

__device__ __forceinline__ unsigned f2bf(float f) {
  // round-to-nearest-even f32 -> bf16 (finite inputs); low 16 bits valid
  unsigned u = __float_as_uint(f);
  unsigned r = u + 0x7fffu + ((u >> 16) & 1u);
  return r >> 16;
}

__device__ __forceinline__ float bf2f(unsigned short u) {
  return __uint_as_float(((unsigned)u) << 16);
}

// ---- prep: x row b -> bf16, and hq[b] = h[b] @ q ; one block per row ----
__global__ __launch_bounds__(256)
void prep_hq_kernel(const float* __restrict__ x,
                    const float* __restrict__ h,
                    const float* __restrict__ q,
                    unsigned short* __restrict__ xb,
                    float* __restrict__ hq) {
  const int b = blockIdx.x, t = threadIdx.x;
  {
    const float* xrow = x + (size_t)b * HDIM;
    unsigned short* xo = xb + (size_t)b * HDIM;
#pragma unroll
    for (int i = 0; i < 4; ++i) {
      const int base = (t * 4 + i) * 8;
      f32x4 v0 = *(const f32x4*)(xrow + base);
      f32x4 v1 = *(const f32x4*)(xrow + base + 4);
      union { unsigned short u[8]; short8 s; } o;
#pragma unroll
      for (int e = 0; e < 4; ++e) {
        o.u[e] = (unsigned short)f2bf(v0[e]);
        o.u[4 + e] = (unsigned short)f2bf(v1[e]);
      }
      *(short8*)(xo + base) = o.s;
    }
  }
  const float* hrow = h + (size_t)b * HDIM;
  f32x4 s = {0.f, 0.f, 0.f, 0.f};
  for (int k = t; k < HDIM; k += 256) {
    float hv = hrow[k];
    f32x4 qv = *(const f32x4*)(q + (size_t)k * RDIM);
    s += hv * qv;
  }
  __shared__ f32x4 red[256];
  red[t] = s;
  __syncthreads();
  for (int off = 128; off > 0; off >>= 1) {
    if (t < off) red[t] += red[t + off];
    __syncthreads();
  }
  if (t == 0) *(f32x4*)(hq + (size_t)b * RDIM) = red[0];
}

// ---- main: partial C for one (jg, ks): 64 rows x 512 cols over K=512 ----
// x-LDS: 64 rows x 512 k bf16, 16B granules; phys granule g' = g ^ (row&7).
__global__ __launch_bounds__(512, 2)
void dplr_main(const float* __restrict__ bmat,
               const unsigned short* __restrict__ xb,
               unsigned short* __restrict__ part) {
  __shared__ __align__(16) unsigned short xs[BDIM * KSLAB];  // 64 KiB

  const int t    = threadIdx.x;
  const int lane = t & 63;
  const int w    = t >> 6;        // 8 waves, wave w owns cols j0..j0+63
  const int c32  = lane & 31;
  const int kh   = lane >> 5;     // k-half of the 32x32x16 fragments

  const int jg = blockIdx.x & 15;
  const int ks = blockIdx.x >> 4;
  const int k0 = ks * KSLAB;

  // ---- stage x slab once (rows 0..63, k in [k0, k0+512)) ----
  {
    const int row = t >> 3;
    const int kq0 = (t & 7) * 8;         // granule base within row (64/row)
    const unsigned short* src = xb + (size_t)row * HDIM + k0 + kq0 * 8;
#pragma unroll
    for (int i = 0; i < 8; ++i) {
      const int g  = row * (KSLAB / 8) + kq0 + i;
      const int gs = g ^ (row & 7);
      *(short8*)&xs[gs * 8] = *(const short8*)(src + i * 8);
    }
  }
  __syncthreads();   // the only barrier in this kernel

  const int j0 = jg * 512 + w * 64;
  const float* b0 = bmat + (size_t)k0 * HDIM + j0 + lane;  // lane <-> col j0+lane

  f32x16 acc[2][2];   // [mt][nt], all indices compile-time after unroll
#pragma unroll
  for (int mt = 0; mt < 2; ++mt)
#pragma unroll
    for (int nt = 0; nt < 2; ++nt)
#pragma unroll
      for (int r = 0; r < 16; ++r) acc[mt][nt][r] = 0.f;

  float LA[32], LB[32];

  // one 32-k tile: 32 loads, each = one contiguous 256B row segment
  auto issue = [&](int tile, float* buf) {
#pragma unroll
    for (int i = 0; i < 32; ++i)
      buf[i] = b0[(size_t)(tile * 32 + i) * HDIM];
  };

  auto conv_mfma = [&](int tile, const float* buf) {
#pragma unroll
    for (int s = 0; s < 2; ++s) {        // two K=16 steps
      unsigned wv[8];
#pragma unroll
      for (int i = 0; i < 8; ++i)
        wv[i] = f2bf(buf[s * 16 + 2 * i]) | (f2bf(buf[s * 16 + 2 * i + 1]) << 16);
      // swap(w[j], w[4+j]): wv[j] becomes tile0 frag word j, wv[4+j] tile1's
#pragma unroll
      for (int j = 0; j < 4; ++j)
        asm volatile("v_permlane32_swap_b32 %0, %1"
                     : "+v"(wv[j]), "+v"(wv[4 + j]));
      union { unsigned u[4]; short8 v; } bf0, bf1;
#pragma unroll
      for (int j = 0; j < 4; ++j) { bf0.u[j] = wv[j]; bf1.u[j] = wv[4 + j]; }
#pragma unroll
      for (int mt = 0; mt < 2; ++mt) {
        const int row = mt * 32 + c32;
        const int gg  = row * (KSLAB / 8) + tile * 4 + s * 2 + kh;
        const int gs  = gg ^ (row & 7);
        short8 af = *(const short8*)&xs[gs * 8];
        acc[mt][0] = __builtin_amdgcn_mfma_f32_32x32x16_bf16(af, bf0.v, acc[mt][0], 0, 0, 0);
        acc[mt][1] = __builtin_amdgcn_mfma_f32_32x32x16_bf16(af, bf1.v, acc[mt][1], 0, 0, 0);
      }
    }
  };

  issue(0, LA);
  for (int tile = 0; tile < NKTILE; tile += 2) {
    issue(tile + 1, LB);                        // next tile in flight
    conv_mfma(tile, LA);                        // consume (vmcnt(32))
    if (tile + 2 < NKTILE) issue(tile + 2, LA);
    conv_mfma(tile + 1, LB);
  }

  // partial write (bf16): part[ks][row][j]
  // C/D 32x32 layout: col = lane&31, row = (reg&3) + 8*(reg>>2) + 4*kh
  unsigned short* pb = part + (size_t)ks * BDIM * HDIM;
#pragma unroll
  for (int mt = 0; mt < 2; ++mt)
#pragma unroll
    for (int nt = 0; nt < 2; ++nt)
#pragma unroll
      for (int reg = 0; reg < 16; ++reg) {
        const int row = mt * 32 + (reg & 3) + 8 * (reg >> 2) + 4 * kh;
        const int col = j0 + nt * 32 + c32;
        pb[(size_t)row * HDIM + col] = (unsigned short)f2bf(acc[mt][nt][reg]);
      }
}

// ---- combine: out = sum_ks part + h*a + hq @ p^T ----
__global__ __launch_bounds__(256)
void combine_kernel(const unsigned short* __restrict__ part,
                    const float* __restrict__ h,
                    const float* __restrict__ adiag,
                    const float* __restrict__ pvec,
                    const float* __restrict__ hq,
                    float* __restrict__ out) {
  const int tid  = blockIdx.x * 256 + threadIdx.x;
  const int base = tid * 8;            // flat into [64][8192]
  const int row  = base >> 13;
  const int j    = base & 8191;

  float s[8];
#pragma unroll
  for (int e = 0; e < 8; ++e) s[e] = 0.f;
  const unsigned short* pp = part + (size_t)row * HDIM + j;
#pragma unroll
  for (int ks = 0; ks < KSPLIT; ++ks) {
    union { unsigned short u[8]; short8 v; } pv;
    pv.v = *(const short8*)(pp + (size_t)ks * BDIM * HDIM);
#pragma unroll
    for (int e = 0; e < 8; ++e) s[e] += bf2f(pv.u[e]);
  }
  const f32x4 hv0 = *(const f32x4*)(h + (size_t)row * HDIM + j);
  const f32x4 hv1 = *(const f32x4*)(h + (size_t)row * HDIM + j + 4);
  const f32x4 a0  = *(const f32x4*)(adiag + j);
  const f32x4 a1  = *(const f32x4*)(adiag + j + 4);
  const f32x4 hqv = *(const f32x4*)(hq + (size_t)row * RDIM);

  float res[8];
#pragma unroll
  for (int e = 0; e < 4; ++e) {
    const f32x4 pv = *(const f32x4*)(pvec + (size_t)(j + e) * RDIM);
    res[e] = s[e] + hv0[e] * a0[e] +
             hqv[0] * pv[0] + hqv[1] * pv[1] + hqv[2] * pv[2] + hqv[3] * pv[3];
  }
#pragma unroll
  for (int e = 0; e < 4; ++e) {
    const f32x4 pv = *(const f32x4*)(pvec + (size_t)(j + 4 + e) * RDIM);
    res[4 + e] = s[4 + e] + hv1[e] * a1[e] +
                 hqv[0] * pv[0] + hqv[1] * pv[1] + hqv[2] * pv[2] + hqv[3] * pv[3];
  }
  f32x4 o0 = {res[0], res[1], res[2], res[3]};
  f32x4 o1 = {res[4], res[5], res[6], res[7]};
  *(f32x4*)(out + (size_t)row * HDIM + j) = o0;
  *(f32x4*)(out + (size_t)row * HDIM + j + 4) = o1;
}

extern "C" void kernel_launch(void* const* d_in, const int* in_sizes, int n_in,
                              void* d_out, int out_size, void* d_ws, size_t ws_size,
                              hipStream_t stream) {
  const float* h     = (const float*)d_in[0];
  const float* x     = (const float*)d_in[1];
  const float* adiag = (const float*)d_in[2];
  const float* pvec  = (const float*)d_in[3];
  const float* qvec  = (const float*)d_in[4];
  const float* bmat  = (const float*)d_in[5];
  float* out = (float*)d_out;

  unsigned short* xb = (unsigned short*)d_ws;                           // 1 MiB
  float* hqbuf = (float*)((char*)d_ws + ((size_t)1 << 20));             // 1 KiB
  unsigned short* part = (unsigned short*)((char*)d_ws + ((size_t)2 << 20));  // 16 MiB

  prep_hq_kernel<<<BDIM, 256, 0, stream>>>(x, h, qvec, xb, hqbuf);
  dplr_main<<<KSPLIT * 16, 512, 0, stream>>>(bmat, xb, part);
  combine_kernel<<<(BDIM * HDIM / 8) / 256, 256, 0, stream>>>(part, h, adiag, pvec, hqbuf, out);
}